// Round 1
// baseline (190.450 us; speedup 1.0000x reference)
//
#include <hip/hip_runtime.h>

// Problem constants (from reference)
#define BATCH 512
#define IN_DIM 4096
// LAYER_IDX = [0, 4096, 6144, 7168, 7680, 7682]
// layer1: s=4096 dim=2048 ebase=0       hs=0
// layer2: s=6144 dim=1024 ebase=262144  hs=2048
// layer3: s=7168 dim=512  ebase=393216  hs=3072
// out:    s=7680 dim=2    ebase=458752
#define FAN_IN 128
#define EPS 1e-5f

// ---------------------------------------------------------------------------
// x [B, IN_DIM] row-major  ->  acts [IN_DIM, B] node-major (32x32 LDS tiles)
__global__ void transpose_x(const float* __restrict__ x, float* __restrict__ acts) {
    __shared__ float tile[32][33];  // +1 pad breaks bank conflicts
    const int f0 = blockIdx.x * 32;
    const int b0 = blockIdx.y * 32;
    const int tx = threadIdx.x;     // 0..31
    const int ty = threadIdx.y;     // 0..7
#pragma unroll
    for (int i = 0; i < 32; i += 8)
        tile[ty + i][tx] = x[(size_t)(b0 + ty + i) * IN_DIM + f0 + tx];
    __syncthreads();
#pragma unroll
    for (int i = 0; i < 32; i += 8)
        acts[(size_t)(f0 + ty + i) * BATCH + b0 + tx] = tile[tx][ty + i];
}

// ---------------------------------------------------------------------------
// Zero the LN stats scratch (3 layers x (sum[512] + sumsq[512]))
__global__ void zero_stats(float* __restrict__ stats) {
    int idx = blockIdx.x * 256 + threadIdx.x;
    if (idx < 3 * 2 * BATCH) stats[idx] = 0.0f;
}

// ---------------------------------------------------------------------------
// One block per target node. Stage the node's 128 (w, src) pairs in LDS,
// 256 threads cover 512 batch columns (2 each), coalesced reads of
// acts[src*512 + b]. Writes raw pre-LN activations (+bias).
__global__ void gather_layer(float* __restrict__ acts,
                             const float* __restrict__ weight,
                             const int* __restrict__ edge_src,
                             const float* __restrict__ bias,
                             int s, int ebase) {
    __shared__ float w_s[FAN_IN];
    __shared__ int   src_s[FAN_IN];
    const int tid = threadIdx.x;
    const int t = s + blockIdx.x;
    const int eb = ebase + blockIdx.x * FAN_IN;
    if (tid < FAN_IN) {
        w_s[tid]   = weight[eb + tid];
        src_s[tid] = edge_src[eb + tid];
    }
    __syncthreads();

    const int b = tid;  // and b+256
    float acc0 = 0.0f, acc1 = 0.0f;
#pragma unroll 8
    for (int k = 0; k < FAN_IN; ++k) {
        const float w = w_s[k];
        const float* row = acts + (size_t)src_s[k] * BATCH;
        acc0 += w * row[b];
        acc1 += w * row[b + 256];
    }
    const float bv = bias[t - IN_DIM];
    acts[(size_t)t * BATCH + b]       = acc0 + bv;
    acts[(size_t)t * BATCH + b + 256] = acc1 + bv;
}

// ---------------------------------------------------------------------------
// Per-batch-column sum & sumsq over the layer's nodes.
// Block = 64 batch lanes x 4 node lanes. grid = (8 batch groups, chunks).
__global__ void ln_stats(const float* __restrict__ acts, float* __restrict__ stats,
                         int s, int dim) {
    const int bLane = threadIdx.x & 63;
    const int nLane = threadIdx.x >> 6;          // 0..3
    const int b = blockIdx.x * 64 + bLane;
    const int stride = 4 * gridDim.y;
    float sum = 0.0f, sq = 0.0f;
    for (int n = blockIdx.y * 4 + nLane; n < dim; n += stride) {
        const float v = acts[(size_t)(s + n) * BATCH + b];
        sum += v;
        sq  += v * v;
    }
    __shared__ float ls[4][64];
    __shared__ float lq[4][64];
    ls[nLane][bLane] = sum;
    lq[nLane][bLane] = sq;
    __syncthreads();
    if (nLane == 0) {
        sum = ls[0][bLane] + ls[1][bLane] + ls[2][bLane] + ls[3][bLane];
        sq  = lq[0][bLane] + lq[1][bLane] + lq[2][bLane] + lq[3][bLane];
        atomicAdd(&stats[b], sum);
        atomicAdd(&stats[BATCH + b], sq);
    }
}

// ---------------------------------------------------------------------------
// In-place LayerNorm (over layer nodes, per batch column) + ReLU.
__global__ void ln_apply(float* __restrict__ acts, const float* __restrict__ stats,
                         const float* __restrict__ gamma, const float* __restrict__ beta,
                         int s, int dim, int hs) {
    const int idx = blockIdx.x * 256 + threadIdx.x;  // [0, dim*512)
    const int n = idx >> 9;       // idx / 512
    const int b = idx & 511;      // idx % 512
    const float inv = 1.0f / (float)dim;
    const float mean = stats[b] * inv;
    const float var  = stats[BATCH + b] * inv - mean * mean;
    const float rstd = rsqrtf(var + EPS);
    float v = acts[(size_t)(s + n) * BATCH + b];
    v = gamma[hs + n] * (v - mean) * rstd + beta[hs + n];
    acts[(size_t)(s + n) * BATCH + b] = fmaxf(v, 0.0f);
}

// ---------------------------------------------------------------------------
// Output layer: 2 nodes, gathers into d_out transposed: out[b*2 + j].
__global__ void gather_out(const float* __restrict__ acts,
                           const float* __restrict__ weight,
                           const int* __restrict__ edge_src,
                           const float* __restrict__ bias,
                           float* __restrict__ out) {
    __shared__ float w_s[FAN_IN];
    __shared__ int   src_s[FAN_IN];
    const int tid = threadIdx.x;
    const int j = blockIdx.x;                    // 0..1
    const int eb = 458752 + j * FAN_IN;
    if (tid < FAN_IN) {
        w_s[tid]   = weight[eb + tid];
        src_s[tid] = edge_src[eb + tid];
    }
    __syncthreads();

    const int b = tid;
    float acc0 = 0.0f, acc1 = 0.0f;
#pragma unroll 8
    for (int k = 0; k < FAN_IN; ++k) {
        const float w = w_s[k];
        const float* row = acts + (size_t)src_s[k] * BATCH;
        acc0 += w * row[b];
        acc1 += w * row[b + 256];
    }
    const float bv = bias[(7680 + j) - IN_DIM];
    out[(size_t)b * 2 + j]         = acc0 + bv;
    out[(size_t)(b + 256) * 2 + j] = acc1 + bv;
}

// ---------------------------------------------------------------------------
extern "C" void kernel_launch(void* const* d_in, const int* in_sizes, int n_in,
                              void* d_out, int out_size, void* d_ws, size_t ws_size,
                              hipStream_t stream) {
    const float* x        = (const float*)d_in[0];  // [512, 4096]
    const float* weight   = (const float*)d_in[1];  // [459008]
    const float* bias     = (const float*)d_in[2];  // [3586]
    const float* ln_gamma = (const float*)d_in[3];  // [3584]
    const float* ln_beta  = (const float*)d_in[4];  // [3584]
    const int*   edge_src = (const int*)d_in[5];    // [459008]
    // d_in[6] = edge_tgt: implicit in the per-target-contiguous edge layout.
    float* out = (float*)d_out;

    // Workspace layout: acts [7680 x 512] fp32, then 3 x (sum+sumsq)[512].
    float* acts  = (float*)d_ws;
    float* stats = acts + (size_t)7680 * BATCH;   // needs ~15.7 MB total

    zero_stats<<<12, 256, 0, stream>>>(stats);
    transpose_x<<<dim3(IN_DIM / 32, BATCH / 32), dim3(32, 8), 0, stream>>>(x, acts);

    // Layer 1: 4096 -> 2048
    gather_layer<<<2048, 256, 0, stream>>>(acts, weight, edge_src, bias, 4096, 0);
    ln_stats<<<dim3(8, 8), 256, 0, stream>>>(acts, stats + 0, 4096, 2048);
    ln_apply<<<2048 * 2, 256, 0, stream>>>(acts, stats + 0, ln_gamma, ln_beta, 4096, 2048, 0);

    // Layer 2: 2048 -> 1024
    gather_layer<<<1024, 256, 0, stream>>>(acts, weight, edge_src, bias, 6144, 262144);
    ln_stats<<<dim3(8, 8), 256, 0, stream>>>(acts, stats + 1024, 6144, 1024);
    ln_apply<<<1024 * 2, 256, 0, stream>>>(acts, stats + 1024, ln_gamma, ln_beta, 6144, 1024, 2048);

    // Layer 3: 1024 -> 512
    gather_layer<<<512, 256, 0, stream>>>(acts, weight, edge_src, bias, 7168, 393216);
    ln_stats<<<dim3(8, 8), 256, 0, stream>>>(acts, stats + 2048, 7168, 512);
    ln_apply<<<512 * 2, 256, 0, stream>>>(acts, stats + 2048, ln_gamma, ln_beta, 7168, 512, 3072);

    // Output layer: 512 -> 2, straight into d_out (transposed write)
    gather_out<<<2, 256, 0, stream>>>(acts, weight, edge_src, bias, out);
}